// Round 9
// baseline (45.901 us; speedup 1.0000x reference)
//
#include <hip/hip_runtime.h>
#include <math.h>

#define NROW 2048
#define BITS 64
#define MB 1024            /* main-kernel threads (16 waves) */
#define RPB 8              /* rows per block */
#define JQ 2               /* consecutive j's per thread */
#define NBLK (NROW / RPB)  /* 256 main blocks = 1/CU */
#define NWV (MB / 64)      /* 16 waves */
#define MAXPOS 256
#define MAXP2 (MAXPOS / 2)

#define LN2_F   0.6931471805599453f
#define THSCALE 0.7213475204444817f      /* 0.5 * log2(e) */
#define A_SC    7.213475204444817f       /* 5.0 * log2(e) */

// ---------------------------------------------------------------------------
// Kernel 0: bT[k][j] = b[j][k]   (64-row tiles)
// ---------------------------------------------------------------------------
__global__ __launch_bounds__(256) void bt_kernel(const float* __restrict__ b,
                                                 float* __restrict__ bT)
{
    __shared__ float tile[64][65];
    const int t  = threadIdx.x;
    const int j0 = blockIdx.x * 64;
    {
        const int jj = t >> 2, q = t & 3;
        const float4* b4 = reinterpret_cast<const float4*>(b + (size_t)(j0 + jj) * BITS);
#pragma unroll
        for (int m = 0; m < 4; ++m) {
            const float4 v = b4[q * 4 + m];
            const int col = q * 16 + m * 4;
            tile[jj][col + 0] = v.x; tile[jj][col + 1] = v.y;
            tile[jj][col + 2] = v.z; tile[jj][col + 3] = v.w;
        }
    }
    __syncthreads();
    {
        const int k = t >> 2, q = t & 3;
#pragma unroll
        for (int s = 0; s < 4; ++s) {
            float4 v;
            v.x = tile[q * 16 + s * 4 + 0][k];
            v.y = tile[q * 16 + s * 4 + 1][k];
            v.z = tile[q * 16 + s * 4 + 2][k];
            v.w = tile[q * 16 + s * 4 + 3][k];
            *reinterpret_cast<float4*>(&bT[(size_t)k * NROW + j0 + q * 16 + s * 4]) = v;
        }
    }
}

// ---------------------------------------------------------------------------
// Kernel 1 (fused): 256 blocks x 1024 threads, 8 rows per block (1 block/CU).
//   Thread t owns j = 2t, 2t+1 (coalesced float2 bT loads; biT[k][0..7]
//   broadcast as 2x b128 -> 16 FMAs per k).
//   ev = exp2(pos ? -th' : th'+alpha'); En=0 for positives => pos x pos pairs
//   contribute log2(1)=0 exactly (inner loop over ALL j, no neg compaction).
//   Positives' pe scattered via shuffle scan; then (s,m)=(p0+p1, p0*p1) per
//   positive-PAIR precomputed ONCE into LDS (shared by all threads/rows).
//   Pair loop, 2 pairs per log: log2(fma(e^2, m, fma(e, s, 1)))
//     -> 2 fma + 1 log + 1 add per 2 pairs; overflow-safe (8 sigma).
//   loss2 partial from the LDS-staged 8 rows.
// ---------------------------------------------------------------------------
template <bool TR>
__global__ __launch_bounds__(MB) void dhn_main(
    const float* __restrict__ b, const float* __restrict__ bT,
    const int* __restrict__ y,
    float* __restrict__ blockLoss, float* __restrict__ blockValid,
    float* __restrict__ blockQ)
{
    const int br  = blockIdx.x;
    const int i0  = br * RPB;
    const int tid = threadIdx.x;
    const int w = tid >> 6, lane = tid & 63;

    __shared__ __align__(16) float  biT[BITS * RPB];        /* [k][r] */
    __shared__ __align__(16) float  posPe[RPB][MAXPOS + 8];
    __shared__ __align__(16) float2 posSM[RPB][MAXP2 + 4];
    __shared__ int   waveTot[RPB][NWV];
    __shared__ int   waveBase[RPB][NWV];
    __shared__ int   pcnt[RPB];
    __shared__ float wred[NWV], wq[NWV];

    if (tid < BITS * RPB) {
        const int k = tid >> 3, r = tid & 7;
        biT[tid] = b[(size_t)(i0 + r) * BITS + k];
    }
    __syncthreads();

    // ---- dot phase: th[q][r] for j = 2*tid + q ----
    float th[JQ][RPB] = {};
    if constexpr (TR) {
        const float2* bt2 = reinterpret_cast<const float2*>(bT);
        const float4* bi4 = reinterpret_cast<const float4*>(biT);
#pragma unroll 8
        for (int k = 0; k < BITS; ++k) {
            const float2 bj = bt2[k * (NROW / 2) + tid];
            const float4 bA = bi4[k * 2 + 0];
            const float4 bB = bi4[k * 2 + 1];
            th[0][0] += bj.x * bA.x; th[0][1] += bj.x * bA.y;
            th[0][2] += bj.x * bA.z; th[0][3] += bj.x * bA.w;
            th[0][4] += bj.x * bB.x; th[0][5] += bj.x * bB.y;
            th[0][6] += bj.x * bB.z; th[0][7] += bj.x * bB.w;
            th[1][0] += bj.y * bA.x; th[1][1] += bj.y * bA.y;
            th[1][2] += bj.y * bA.z; th[1][3] += bj.y * bA.w;
            th[1][4] += bj.y * bB.x; th[1][5] += bj.y * bB.y;
            th[1][6] += bj.y * bB.z; th[1][7] += bj.y * bB.w;
        }
    } else {
        for (int k = 0; k < BITS; ++k) {
#pragma unroll
            for (int q = 0; q < JQ; ++q) {
                const float v = b[(size_t)(JQ * tid + q) * BITS + k];
#pragma unroll
                for (int r = 0; r < RPB; ++r) th[q][r] += v * biT[k * RPB + r];
            }
        }
    }

    const int2 y2 = reinterpret_cast<const int2*>(y)[tid];
    const int yj[JQ] = { y2.x, y2.y };
    int yr[RPB];
#pragma unroll
    for (int r = 0; r < RPB; ++r) yr[r] = y[i0 + r];

    // ---- exp2 + masks ----
    float ev[JQ][RPB];
    int pm[RPB], cnt[RPB];
#pragma unroll
    for (int r = 0; r < RPB; ++r) {
        int m = 0;
#pragma unroll
        for (int q = 0; q < JQ; ++q) {
            const float t2 = th[q][r] * THSCALE;
            const bool f = (yj[q] == yr[r]);
            ev[q][r] = __builtin_amdgcn_exp2f(f ? -t2 : t2 + A_SC);
            if (f) m |= 1 << q;
        }
        pm[r] = m;
        cnt[r] = __popc(m);
    }

    // ---- prefix scan of positive counts (per row) ----
    int excl[RPB];
#pragma unroll
    for (int r = 0; r < RPB; ++r) {
        int v = cnt[r];
#pragma unroll
        for (int off = 1; off < 64; off <<= 1) {
            const int t2 = __shfl_up(v, off);
            if (lane >= off) v += t2;
        }
        excl[r] = v - cnt[r];
        if (lane == 63) waveTot[r][w] = v;
    }
    __syncthreads();
    if (tid < RPB) {
        int base = 0;
#pragma unroll
        for (int wv = 0; wv < NWV; ++wv) { waveBase[tid][wv] = base; base += waveTot[tid][wv]; }
        pcnt[tid] = base;
    }
    __syncthreads();

    // ---- scatter positives' pe; pad posPe to multiple of 8 with zeros ----
#pragma unroll
    for (int r = 0; r < RPB; ++r) {
        int o = waveBase[r][w] + excl[r];
#pragma unroll
        for (int q = 0; q < JQ; ++q) {
            if ((pm[r] >> q) & 1) {
                if (o < MAXPOS) posPe[r][o] = ev[q][r];
                ++o;
            }
        }
    }
    if (tid < RPB * 8) {
        const int r = tid >> 3, q = tid & 7;
        const int P = pcnt[r] < MAXPOS ? pcnt[r] : MAXPOS;
        const int idx = P + q;
        if (idx < ((P + 7) & ~7)) posPe[r][idx] = 0.f;
    }
    __syncthreads();

    // ---- build (s,m) per positive-pair, once per block ----
    {
        const int r  = tid >> 7;          /* 0..7 */
        const int pp = tid & 127;         /* 0..127 = MAXP2 */
        const int P  = pcnt[r] < MAXPOS ? pcnt[r] : MAXPOS;
        const int P2pad = ((P + 7) & ~7) >> 1;     /* multiple of 4 */
        if (pp < P2pad) {
            const float p0 = posPe[r][2 * pp + 0];
            const float p1 = posPe[r][2 * pp + 1];
            posSM[r][pp] = make_float2(p0 + p1, p0 * p1);
        }
    }
    __syncthreads();

    // ---- pair loop ----
    float total = 0.f;
#pragma unroll
    for (int r = 0; r < RPB; ++r) {
        const int Pc = pcnt[r];
        const int P  = Pc < MAXPOS ? Pc : MAXPOS;
        const int PG = (((P + 7) & ~7) >> 1) >> 2;   /* groups of 4 pairs */
        const float e0  = (pm[r] & 1) ? 0.f : ev[0][r];
        const float e1  = (pm[r] & 2) ? 0.f : ev[1][r];
        const float e20 = e0 * e0;
        const float e21 = e1 * e1;
        float a0 = 0.f, a1 = 0.f;
        const float4* sm4 = reinterpret_cast<const float4*>(&posSM[r][0]);
        for (int g = 0; g < PG; ++g) {
            const float4 A = sm4[2 * g + 0];   /* s0 m0 s1 m1 */
            const float4 B = sm4[2 * g + 1];   /* s2 m2 s3 m3 */
            a0 += __builtin_amdgcn_logf(fmaf(e20, A.y, fmaf(e0, A.x, 1.f)))
                + __builtin_amdgcn_logf(fmaf(e20, A.w, fmaf(e0, A.z, 1.f)))
                + __builtin_amdgcn_logf(fmaf(e20, B.y, fmaf(e0, B.x, 1.f)))
                + __builtin_amdgcn_logf(fmaf(e20, B.w, fmaf(e0, B.z, 1.f)));
            a1 += __builtin_amdgcn_logf(fmaf(e21, A.y, fmaf(e1, A.x, 1.f)))
                + __builtin_amdgcn_logf(fmaf(e21, A.w, fmaf(e1, A.z, 1.f)))
                + __builtin_amdgcn_logf(fmaf(e21, B.y, fmaf(e1, B.x, 1.f)))
                + __builtin_amdgcn_logf(fmaf(e21, B.w, fmaf(e1, B.z, 1.f)));
        }
        const bool valid = (Pc > 0) && (Pc < NROW);
        const float denom = (float)Pc * (float)(NROW - Pc);
        total += valid ? (a0 + a1) / denom : 0.f;
    }
    total *= LN2_F;

    // ---- loss2 partial from LDS-staged rows (8 x 64 = 512 elems) ----
    float q2 = 0.f;
    if (tid < BITS * RPB) {
        const float x  = biT[tid];
        const float sg = (x > 0.f) ? 1.f : ((x < 0.f) ? -1.f : 0.f);
        const float d  = x - sg;
        q2 = d * d;
    }

    // ---- reductions ----
#pragma unroll
    for (int off = 32; off > 0; off >>= 1) {
        total += __shfl_xor(total, off);
        q2    += __shfl_xor(q2, off);
    }
    if (lane == 0) { wred[w] = total; wq[w] = q2; }
    __syncthreads();
    if (tid == 0) {
        float tl = 0.f, tq = 0.f;
#pragma unroll
        for (int v = 0; v < NWV; ++v) { tl += wred[v]; tq += wq[v]; }
        blockLoss[br] = tl;
        blockQ[br]    = tq;
        float vc = 0.f;
#pragma unroll
        for (int r = 0; r < RPB; ++r)
            vc += ((pcnt[r] > 0) && (pcnt[r] < NROW)) ? 1.f : 0.f;
        blockValid[br] = vc;
    }
}

// ---------------------------------------------------------------------------
// Kernel 2: reduce 256 block partials -> 3 outputs
// ---------------------------------------------------------------------------
__global__ __launch_bounds__(256) void dhn_final_kernel(
    const float* __restrict__ blockLoss, const float* __restrict__ blockValid,
    const float* __restrict__ blockQ, float* __restrict__ out)
{
    const int tid = threadIdx.x;
    const int w = tid >> 6, lane = tid & 63;
    __shared__ float r1[4], r2[4], r3[4];

    float sl = 0.f, sv = 0.f, sq = 0.f;
    for (int i = tid; i < NBLK; i += 256) {
        sl += blockLoss[i]; sv += blockValid[i]; sq += blockQ[i];
    }
#pragma unroll
    for (int off = 32; off > 0; off >>= 1) {
        sl += __shfl_xor(sl, off);
        sv += __shfl_xor(sv, off);
        sq += __shfl_xor(sq, off);
    }
    if (lane == 0) { r1[w] = sl; r2[w] = sv; r3[w] = sq; }
    __syncthreads();
    if (tid == 0) {
        float SL = 0.f, SV = 0.f, SQ = 0.f;
#pragma unroll
        for (int v = 0; v < 4; ++v) { SL += r1[v]; SV += r2[v]; SQ += r3[v]; }
        const float loss1 = (SV > 0.f) ? SL / fmaxf(SV, 1.f) : 0.f;
        const float loss2 = SQ / (float)(NROW * BITS);
        out[0] = loss1 + 1.0f * loss2;   /* LAMBDA = 1.0 */
        out[1] = loss1;
        out[2] = loss2;
    }
}

extern "C" void kernel_launch(void* const* d_in, const int* in_sizes, int n_in,
                              void* d_out, int out_size, void* d_ws, size_t ws_size,
                              hipStream_t stream) {
    const float* b = (const float*)d_in[0];
    const int*   y = (const int*)d_in[1];
    float* out = (float*)d_out;

    float* blockLoss  = (float*)d_ws;                      /* [256] */
    float* blockValid = (float*)((char*)d_ws + 4096);      /* [256] */
    float* blockQ     = (float*)((char*)d_ws + 8192);      /* [256] */
    float* bT         = (float*)((char*)d_ws + 16384);     /* [64*2048] */

    const size_t need = 16384 + (size_t)BITS * NROW * sizeof(float);
    if (ws_size >= need) {
        bt_kernel<<<NROW / 64, 256, 0, stream>>>(b, bT);
        dhn_main<true><<<NBLK, MB, 0, stream>>>(b, bT, y, blockLoss, blockValid, blockQ);
    } else {
        dhn_main<false><<<NBLK, MB, 0, stream>>>(b, nullptr, y, blockLoss, blockValid, blockQ);
    }
    dhn_final_kernel<<<1, 256, 0, stream>>>(blockLoss, blockValid, blockQ, out);
}